// Round 10
// baseline (221.290 us; speedup 1.0000x reference)
//
#include <hip/hip_runtime.h>
#include <hip/hip_bf16.h>
#include <math.h>

typedef __attribute__((ext_vector_type(8))) short bf16x8;
typedef __attribute__((ext_vector_type(4))) float f32x4;

#define NROWS 8192
#define DIM   768
#define BM    256
#define BN    256
#define BK    64
#define NT    12   // DIM / BK

#define AS1 __attribute__((address_space(1)))
#define AS3 __attribute__((address_space(3)))

// ---- float <-> order-preserving uint key (for atomicMax on floats) ----
__device__ inline unsigned fkey(float v) {
  unsigned u = __float_as_uint(v);
  return (u & 0x80000000u) ? ~u : (u | 0x80000000u);
}
__device__ inline float funkey(unsigned k) {
  unsigned u = (k & 0x80000000u) ? (k & 0x7fffffffu) : ~k;
  return __uint_as_float(u);
}

// ---- kernel 1: row-normalize ex,ey -> bf16 (BW-shaped: 192 thr = 3 waves,
// one float4 load + one ushort4 store per thread; 768 = 192*4 exactly) ----
__global__ __launch_bounds__(192) void normalize_kernel(
    const float* __restrict__ ex, const float* __restrict__ ey,
    __hip_bfloat16* __restrict__ An, __hip_bfloat16* __restrict__ Bn) {
  int row = blockIdx.x;  // 0..16383: first 8192 = ex, rest = ey
  const float* src;
  __hip_bfloat16* dst;
  if (row < NROWS) {
    src = ex + (size_t)row * DIM;
    dst = An + (size_t)row * DIM;
  } else {
    src = ey + (size_t)(row - NROWS) * DIM;
    dst = Bn + (size_t)(row - NROWS) * DIM;
  }
  int t = threadIdx.x;
  float4 v = ((const float4*)src)[t];
  float ss = v.x * v.x + v.y * v.y + v.z * v.z + v.w * v.w;
#pragma unroll
  for (int s = 1; s < 64; s <<= 1) ss += __shfl_xor(ss, s);
  __shared__ float wsum[3];
  if ((t & 63) == 0) wsum[t >> 6] = ss;
  __syncthreads();
  float tot = wsum[0] + wsum[1] + wsum[2];
  float scale = 1.0f / fmaxf(sqrtf(tot), 1e-8f);
  ushort4 o;
  o.x = __bfloat16_as_ushort(__float2bfloat16(v.x * scale));
  o.y = __bfloat16_as_ushort(__float2bfloat16(v.y * scale));
  o.z = __bfloat16_as_ushort(__float2bfloat16(v.z * scale));
  o.w = __bfloat16_as_ushort(__float2bfloat16(v.w * scale));
  ((ushort4*)dst)[t] = o;
}

// ---- kernel 2: 256x256-tile GEMM + row/col max, ONE PHASE PER K-TILE -----
// 512 thr = 8 waves (2 row x 4 col); per-wave 128x64 output; acc[8][4] f32x4.
// LDS [2 buf][A|B][2 kh][256 rows][64 B] = 128 KB (1 block/CU).
// Phase T (buf = T&1): {24 ds_reads + 64 MFMA (compiler fine-grain lgkm
// interleave) -> BAR1 -> stage tile T+2 into buf (dead: all waves' reads of
// buf done before BAR1) -> vmcnt(8) (drains tile T+1's 8 loads, leaves
// T+2's 8 in flight) -> BAR2}.  Head (first-read latency + barrier skew)
// amortized over a 2064-cyc MFMA body instead of 8x smaller phases
// (round-6 diagnosis: 196 cyc head per 516-cyc phase = 72% efficiency).
// Prologue stages tiles 0,1 with vmcnt(8); peel T=NT-2 (vmcnt(0), no stage),
// T=NT-1 (bare).  XCD swizzle: 1024 blocks % 8 == 0 -> bijective chunked
// remap, B-panels reused within an XCD's private L2.
// Swizzle (measured 0 bank conflicts rounds 4-8): 16B slot = l4^((row>>1)&3).
__global__ __launch_bounds__(512, 1) void gemm_max_kernel(
    const __hip_bfloat16* __restrict__ A, const __hip_bfloat16* __restrict__ B,
    unsigned* __restrict__ rowKey, unsigned* __restrict__ colKey) {
  __shared__ __align__(16) char lds[131072];
  const int t = threadIdx.x;
  const int lane = t & 63;
  const int wid = t >> 6;       // 0..7
  const int wr = wid >> 2;      // 0..1
  const int wc = wid & 3;       // 0..3
  // XCD-aware bijective remap of the 1D grid (1024 = 8 XCDs x 128)
  const int flat = blockIdx.x;
  const int bswz = (flat & 7) * 128 + (flat >> 3);
  const int brow = (bswz & 31) * BM;
  const int bcol = (bswz >> 5) * BN;
  const int l15 = lane & 15, l4 = lane >> 4;

  // staging source pointers (per-thread, pre-swizzled), region halves c=0/1
  const int c0L = t * 16;            // LDS byte offset within region, half 0
  const int c1L = 8192 + t * 16;     // half 1
  const int r0 = c0L >> 6, r1 = c1L >> 6;
  const int s0 = ((c0L >> 4) & 3) ^ ((r0 >> 1) & 3);
  const int s1 = ((c1L >> 4) & 3) ^ ((r1 >> 1) & 3);
  const char* gA0 = (const char*)(A + (size_t)(brow + r0) * DIM) + s0 * 16;
  const char* gA1 = (const char*)(A + (size_t)(brow + r1) * DIM) + s1 * 16;
  const char* gB0 = (const char*)(B + (size_t)(bcol + r0) * DIM) + s0 * 16;
  const char* gB1 = (const char*)(B + (size_t)(bcol + r1) * DIM) + s1 * 16;

  // stage one K-half (kh) of one matrix for tile tt into buffer buf
  auto stage_ = [&](int mat, int buf, int tt, int kh) {
    char* base = lds + (buf << 16) + (mat << 15) + (kh << 14);
    const char* p0 = (mat ? gB0 : gA0) + tt * 128 + kh * 64;
    const char* p1 = (mat ? gB1 : gA1) + tt * 128 + kh * 64;
    __builtin_amdgcn_global_load_lds((const AS1 void*)p0,
        (AS3 void*)(base + c0L), 16, 0, 0);
    __builtin_amdgcn_global_load_lds((const AS1 void*)p1,
        (AS3 void*)(base + c1L), 16, 0, 0);
  };

  f32x4 acc[8][4];
#pragma unroll
  for (int m = 0; m < 8; ++m)
#pragma unroll
    for (int n = 0; n < 4; ++n) acc[m][n] = (f32x4)0.0f;

  // one full K-tile of MFMAs from buffer buf (24 ds_reads, 64 MFMA)
  auto compute_tile = [&](int buf) {
    const char* base = lds + (buf << 16);
#pragma unroll
    for (int kk = 0; kk < 2; ++kk) {
      const char* rA = base + (kk << 14);
      const char* rB = base + 32768 + (kk << 14);
      bf16x8 af[8], bfr[4];
#pragma unroll
      for (int m = 0; m < 8; ++m) {
        int r = wr * 128 + m * 16 + l15;
        af[m] = *(const bf16x8*)(rA + r * 64 + ((l4 ^ ((r >> 1) & 3)) << 4));
      }
#pragma unroll
      for (int n = 0; n < 4; ++n) {
        int r = wc * 64 + n * 16 + l15;
        bfr[n] = *(const bf16x8*)(rB + r * 64 + ((l4 ^ ((r >> 1) & 3)) << 4));
      }
      __builtin_amdgcn_s_setprio(1);
#pragma unroll
      for (int m = 0; m < 8; ++m)
#pragma unroll
        for (int n = 0; n < 4; ++n)
          acc[m][n] = __builtin_amdgcn_mfma_f32_16x16x32_bf16(
              af[m], bfr[n], acc[m][n], 0, 0, 0);
      __builtin_amdgcn_s_setprio(0);
    }
  };

#define BAR __builtin_amdgcn_s_barrier()
#define VMW(N) asm volatile("s_waitcnt vmcnt(" #N ")" ::: "memory")

  // prologue: stage tiles 0 and 1; drain tile 0 (leave tile 1's 8 in flight)
  stage_(0, 0, 0, 0); stage_(0, 0, 0, 1); stage_(1, 0, 0, 0); stage_(1, 0, 0, 1);
  stage_(0, 1, 1, 0); stage_(0, 1, 1, 1); stage_(1, 1, 1, 0); stage_(1, 1, 1, 1);
  VMW(8);
  BAR;

  for (int T = 0; T < NT - 2; ++T) {
    int buf = T & 1;
    compute_tile(buf);
    BAR;  // all waves' reads of buf done -> safe to overwrite
    stage_(0, buf, T + 2, 0); stage_(0, buf, T + 2, 1);
    stage_(1, buf, T + 2, 0); stage_(1, buf, T + 2, 1);
    VMW(8);  // tile T+1 landed; tile T+2's 8 loads stay in flight
    BAR;
  }
  // T = NT-2: no stage; drain tile NT-1 fully
  compute_tile(0);
  VMW(0);
  BAR;
  // T = NT-1
  compute_tile(1);

#undef BAR
#undef VMW

  // ---- epilogue: row/col maxes of this block's 256x256 tile ----
  // D layout (16x16x32 bf16): col = lane&15, row = (lane>>4)*4 + reg
#pragma unroll
  for (int m = 0; m < 8; ++m) {
#pragma unroll
    for (int j = 0; j < 4; ++j) {
      float v = fmaxf(fmaxf(acc[m][0][j], acc[m][1][j]),
                      fmaxf(acc[m][2][j], acc[m][3][j]));
#pragma unroll
      for (int s = 1; s < 16; s <<= 1) v = fmaxf(v, __shfl_xor(v, s));
      if (l15 == 0) {
        int grow = brow + wr * 128 + m * 16 + l4 * 4 + j;
        atomicMax(&rowKey[grow], fkey(v));
      }
    }
  }
#pragma unroll
  for (int n = 0; n < 4; ++n) {
    float v = -1e30f;
#pragma unroll
    for (int m = 0; m < 8; ++m)
#pragma unroll
      for (int j = 0; j < 4; ++j) v = fmaxf(v, acc[m][n][j]);
    v = fmaxf(v, __shfl_xor(v, 16));
    v = fmaxf(v, __shfl_xor(v, 32));
    if (l4 == 0) {
      int gcol = bcol + wc * 64 + n * 16 + l15;
      atomicMax(&colKey[gcol], fkey(v));
    }
  }
}

// ---- kernel 3: entropy terms from the max arrays ----
__global__ __launch_bounds__(256) void finalize_kernel(
    const unsigned* __restrict__ rowKey, const unsigned* __restrict__ colKey,
    float* __restrict__ out) {
  const unsigned* src = (blockIdx.x == 0) ? rowKey : colKey;
  int t = threadIdx.x;
  const float log_norm = -0.6957949819f;  // -log(0.8) - 0.5*log(2*pi)
  float s = 0.0f;
  for (int i = t; i < NROWS; i += 256) {
    float c = funkey(src[i]);
    float lp = -(c * c) * 0.78125f + log_norm;  // 1/(2*0.8^2) = 0.78125
    s += __expf(lp) * lp;
  }
#pragma unroll
  for (int sh = 1; sh < 64; sh <<= 1) s += __shfl_xor(s, sh);
  __shared__ float wsum[4];
  if ((t & 63) == 0) wsum[t >> 6] = s;
  __syncthreads();
  if (t == 0) out[blockIdx.x] = -(wsum[0] + wsum[1] + wsum[2] + wsum[3]);
}

extern "C" void kernel_launch(void* const* d_in, const int* in_sizes, int n_in,
                              void* d_out, int out_size, void* d_ws, size_t ws_size,
                              hipStream_t stream) {
  const float* ex = (const float*)d_in[0];
  const float* ey = (const float*)d_in[1];
  char* ws = (char*)d_ws;
  __hip_bfloat16* An = (__hip_bfloat16*)ws;                              // 12.6 MB
  __hip_bfloat16* Bn = (__hip_bfloat16*)(ws + (size_t)NROWS * DIM * 2);  // 12.6 MB
  unsigned* rowKey = (unsigned*)(ws + (size_t)NROWS * DIM * 4);          // 32 KB
  unsigned* colKey = rowKey + NROWS;                                     // 32 KB

  hipMemsetAsync(rowKey, 0, 2 * NROWS * sizeof(unsigned), stream);
  normalize_kernel<<<2 * NROWS, 192, 0, stream>>>(ex, ey, An, Bn);
  gemm_max_kernel<<<1024, 512, 0, stream>>>(An, Bn, rowKey, colKey);
  finalize_kernel<<<2, 256, 0, stream>>>(rowKey, colKey, (float*)d_out);
}

// Round 11
// 205.608 us; speedup vs baseline: 1.0763x; 1.0763x over previous
//
#include <hip/hip_runtime.h>
#include <hip/hip_bf16.h>
#include <math.h>

typedef __attribute__((ext_vector_type(8))) short bf16x8;
typedef __attribute__((ext_vector_type(4))) float f32x4;

#define NROWS 8192
#define DIM   768
#define BM    256
#define BN    256
#define BK    64
#define NT    12   // DIM / BK

#define AS1 __attribute__((address_space(1)))
#define AS3 __attribute__((address_space(3)))

// ---- float <-> order-preserving uint key (for atomicMax on floats) ----
__device__ inline unsigned fkey(float v) {
  unsigned u = __float_as_uint(v);
  return (u & 0x80000000u) ? ~u : (u | 0x80000000u);
}
__device__ inline float funkey(unsigned k) {
  unsigned u = (k & 0x80000000u) ? (k & 0x7fffffffu) : ~k;
  return __uint_as_float(u);
}

// ---- kernel 1: row-normalize ex,ey -> bf16.  WAVE-PER-ROW: 4 waves/block,
// no LDS, no __syncthreads; 3x float4 load + shuffle reduce + 3x ushort4
// store per lane.  Also zeroes the rowKey/colKey arrays (kills the memset
// dispatch): wave handling global row g zeroes key[g] (16384 keys total).
__global__ __launch_bounds__(256) void normalize_kernel(
    const float* __restrict__ ex, const float* __restrict__ ey,
    __hip_bfloat16* __restrict__ An, __hip_bfloat16* __restrict__ Bn,
    unsigned* __restrict__ keys) {
  const int w = threadIdx.x >> 6, lane = threadIdx.x & 63;
  const int g = blockIdx.x * 4 + w;  // 0..16383
  const float* src;
  __hip_bfloat16* dst;
  if (g < NROWS) {
    src = ex + (size_t)g * DIM;
    dst = An + (size_t)g * DIM;
  } else {
    src = ey + (size_t)(g - NROWS) * DIM;
    dst = Bn + (size_t)(g - NROWS) * DIM;
  }
  float4 v0 = ((const float4*)src)[lane];
  float4 v1 = ((const float4*)src)[64 + lane];
  float4 v2 = ((const float4*)src)[128 + lane];
  float ss = v0.x * v0.x + v0.y * v0.y + v0.z * v0.z + v0.w * v0.w
           + v1.x * v1.x + v1.y * v1.y + v1.z * v1.z + v1.w * v1.w
           + v2.x * v2.x + v2.y * v2.y + v2.z * v2.z + v2.w * v2.w;
#pragma unroll
  for (int s = 1; s < 64; s <<= 1) ss += __shfl_xor(ss, s);
  float scale = 1.0f / fmaxf(sqrtf(ss), 1e-8f);
  ushort4 o;
#define CVT4(V) o.x = __bfloat16_as_ushort(__float2bfloat16(V.x * scale)); \
                o.y = __bfloat16_as_ushort(__float2bfloat16(V.y * scale)); \
                o.z = __bfloat16_as_ushort(__float2bfloat16(V.z * scale)); \
                o.w = __bfloat16_as_ushort(__float2bfloat16(V.w * scale))
  CVT4(v0); ((ushort4*)dst)[lane] = o;
  CVT4(v1); ((ushort4*)dst)[64 + lane] = o;
  CVT4(v2); ((ushort4*)dst)[128 + lane] = o;
#undef CVT4
  if (lane == 0) keys[g] = 0u;  // init for atomicMax (fkey(x) > 0 for all x)
}

// ---- kernel 2: 256x256-tile 8-phase fused GEMM + row/col max -------------
// ROUND-6 STRUCTURE VERBATIM (measured 114 us, 69 MB fetch, 0 conflicts).
// 512 threads = 8 waves (2 row-groups x 4 col-groups); per-wave 128x64 out.
// LDS: [2 buf][A|B][2 K-half][256 rows][64 B].  Stage ledger (iter computes
// tiles t,t+1):
//   ph1:A(t+1,1) ph2:B(t+1,1) ph3:A(t+2,0) ph4:B(t+2,0)+vmcnt(4)
//   ph5:A(t+2,1) ph6:B(t+2,1) ph7:A(t+3,0) ph8:B(t+3,0)+vmcnt(4)
// ONE barrier per phase, AFTER the vmcnt.  Compiler emits fine-grained
// lgkm waits for the ds_reads (no explicit lgkmcnt(0)/sched_barrier).
// Final iteration peeled with vmcnt(0) at its ph4.
// Grid: dim3(32,32), blockIdx.x=row tile -- round-robin dispatch gives each
// XCD a ~4x8 patch (~4.7 MB ~ L2); round-10's column-chunk remap tripled
// FETCH_SIZE (69->203 MB).  Do NOT re-add a 1D XCD swizzle here.
// Swizzle: 16B slot = l4 ^ ((row>>1)&3) (64-B rows; measured 0 conflicts).
__global__ __launch_bounds__(512, 2) void gemm_max_kernel(
    const __hip_bfloat16* __restrict__ A, const __hip_bfloat16* __restrict__ B,
    unsigned* __restrict__ rowKey, unsigned* __restrict__ colKey) {
  __shared__ __align__(16) char lds[131072];
  const int t = threadIdx.x;
  const int lane = t & 63;
  const int wid = t >> 6;       // 0..7
  const int wr = wid >> 2;      // 0..1
  const int wc = wid & 3;       // 0..3
  const int brow = blockIdx.x * BM;
  const int bcol = blockIdx.y * BN;
  const int l15 = lane & 15, l4 = lane >> 4;

  // stage one K-half of one matrix for tile tt: 16 KB = 2 x (512 thr x 16 B)
  auto stage_ = [&](int mat, int tt, int kh) {
    char* base = lds + ((tt & 1) << 16) + (mat << 15) + (kh << 14);
    const __hip_bfloat16* G = mat ? B : A;
    const int bb = mat ? bcol : brow;
#pragma unroll
    for (int c = 0; c < 2; ++c) {
      int L = c * 8192 + t * 16;          // linear LDS byte offset in region
      int r = L >> 6;                     // row 0..255
      int sl = (L >> 4) & 3;              // linear 16B slot
      int ssl = sl ^ ((r >> 1) & 3);      // pre-swizzled source slot
      const __hip_bfloat16* g =
          G + (size_t)(bb + r) * DIM + tt * BK + kh * 32 + ssl * 8;
      __builtin_amdgcn_global_load_lds(
          (const AS1 void*)g, (AS3 void*)(base + L), 16, 0, 0);
    }
  };

  f32x4 acc[8][4];
#pragma unroll
  for (int m = 0; m < 8; ++m)
#pragma unroll
    for (int n = 0; n < 4; ++n) acc[m][n] = (f32x4)0.0f;
  bf16x8 bfr[4];

#define NOPW  do {} while (0)
#define VM4   asm volatile("s_waitcnt vmcnt(4)" ::: "memory")
#define VM0   asm volatile("s_waitcnt vmcnt(0)" ::: "memory")

#define PHASE(TT, KK, OH, STAGESTMT, WAITSTMT)                                 \
  do {                                                                         \
    const char* regA_ = lds + (((TT) & 1) << 16) + ((KK) << 14);               \
    const char* regB_ = regA_ + 32768;                                         \
    bf16x8 af[4];                                                              \
    _Pragma("unroll") for (int m_ = 0; m_ < 4; ++m_) {                         \
      int r_ = wr * 128 + ((OH) * 4 + m_) * 16 + l15;                          \
      af[m_] = *(const bf16x8*)(regA_ + r_ * 64 +                              \
                                ((l4 ^ ((r_ >> 1) & 3)) << 4));                \
    }                                                                          \
    if ((OH) == 0) {                                                           \
      _Pragma("unroll") for (int n_ = 0; n_ < 4; ++n_) {                       \
        int r_ = wc * 64 + n_ * 16 + l15;                                      \
        bfr[n_] = *(const bf16x8*)(regB_ + r_ * 64 +                           \
                                   ((l4 ^ ((r_ >> 1) & 3)) << 4));             \
      }                                                                        \
    }                                                                          \
    STAGESTMT;                                                                 \
    WAITSTMT;                                                                  \
    __builtin_amdgcn_s_setprio(1);                                             \
    _Pragma("unroll") for (int m_ = 0; m_ < 4; ++m_)                           \
      _Pragma("unroll") for (int n_ = 0; n_ < 4; ++n_)                         \
        acc[(OH) * 4 + m_][n_] = __builtin_amdgcn_mfma_f32_16x16x32_bf16(      \
            af[m_], bfr[n_], acc[(OH) * 4 + m_][n_], 0, 0, 0);                 \
    __builtin_amdgcn_s_setprio(0);                                             \
    __builtin_amdgcn_s_barrier();                                              \
  } while (0)

  // prologue: tile0 fully + tile1 K-half0; drain tile0, leave (1,0) in flight
  stage_(0, 0, 0); stage_(1, 0, 0);
  stage_(0, 0, 1); stage_(1, 0, 1);
  stage_(0, 1, 0); stage_(1, 1, 0);
  VM4;
  __builtin_amdgcn_s_barrier();

  for (int t0 = 0; t0 < NT - 2; t0 += 2) {
    PHASE(t0,     0, 0, stage_(0, t0 + 1, 1), NOPW);
    PHASE(t0,     0, 1, stage_(1, t0 + 1, 1), NOPW);
    PHASE(t0,     1, 0, stage_(0, t0 + 2, 0), NOPW);
    PHASE(t0,     1, 1, stage_(1, t0 + 2, 0), VM4);
    PHASE(t0 + 1, 0, 0, stage_(0, t0 + 2, 1), NOPW);
    PHASE(t0 + 1, 0, 1, stage_(1, t0 + 2, 1), NOPW);
    PHASE(t0 + 1, 1, 0, stage_(0, t0 + 3, 0), NOPW);
    PHASE(t0 + 1, 1, 1, stage_(1, t0 + 3, 0), VM4);
  }
  // peeled final iteration (t0 = NT-2): stages for (NT-1,1) only, full drain
  PHASE(NT - 2, 0, 0, stage_(0, NT - 1, 1), NOPW);
  PHASE(NT - 2, 0, 1, stage_(1, NT - 1, 1), NOPW);
  PHASE(NT - 2, 1, 0, NOPW, NOPW);
  PHASE(NT - 2, 1, 1, NOPW, VM0);
  PHASE(NT - 1, 0, 0, NOPW, NOPW);
  PHASE(NT - 1, 0, 1, NOPW, NOPW);
  PHASE(NT - 1, 1, 0, NOPW, NOPW);
  PHASE(NT - 1, 1, 1, NOPW, NOPW);
#undef PHASE
#undef NOPW
#undef VM4
#undef VM0

  // ---- epilogue: row/col maxes of this block's 256x256 tile ----
  // D layout (16x16x32 bf16): col = lane&15, row = (lane>>4)*4 + reg
#pragma unroll
  for (int m = 0; m < 8; ++m) {
#pragma unroll
    for (int j = 0; j < 4; ++j) {
      float v = fmaxf(fmaxf(acc[m][0][j], acc[m][1][j]),
                      fmaxf(acc[m][2][j], acc[m][3][j]));
#pragma unroll
      for (int s = 1; s < 16; s <<= 1) v = fmaxf(v, __shfl_xor(v, s));
      if (l15 == 0) {
        int grow = brow + wr * 128 + m * 16 + l4 * 4 + j;
        atomicMax(&rowKey[grow], fkey(v));
      }
    }
  }
#pragma unroll
  for (int n = 0; n < 4; ++n) {
    float v = -1e30f;
#pragma unroll
    for (int m = 0; m < 8; ++m)
#pragma unroll
      for (int j = 0; j < 4; ++j) v = fmaxf(v, acc[m][n][j]);
    v = fmaxf(v, __shfl_xor(v, 16));
    v = fmaxf(v, __shfl_xor(v, 32));
    if (l4 == 0) {
      int gcol = bcol + wc * 64 + n * 16 + l15;
      atomicMax(&colKey[gcol], fkey(v));
    }
  }
}

// ---- kernel 3: entropy terms from the max arrays ----
__global__ __launch_bounds__(256) void finalize_kernel(
    const unsigned* __restrict__ rowKey, const unsigned* __restrict__ colKey,
    float* __restrict__ out) {
  const unsigned* src = (blockIdx.x == 0) ? rowKey : colKey;
  int t = threadIdx.x;
  const float log_norm = -0.6957949819f;  // -log(0.8) - 0.5*log(2*pi)
  float s = 0.0f;
  for (int i = t; i < NROWS; i += 256) {
    float c = funkey(src[i]);
    float lp = -(c * c) * 0.78125f + log_norm;  // 1/(2*0.8^2) = 0.78125
    s += __expf(lp) * lp;
  }
#pragma unroll
  for (int sh = 1; sh < 64; sh <<= 1) s += __shfl_xor(s, sh);
  __shared__ float wsum[4];
  if ((t & 63) == 0) wsum[t >> 6] = s;
  __syncthreads();
  if (t == 0) out[blockIdx.x] = -(wsum[0] + wsum[1] + wsum[2] + wsum[3]);
}

extern "C" void kernel_launch(void* const* d_in, const int* in_sizes, int n_in,
                              void* d_out, int out_size, void* d_ws, size_t ws_size,
                              hipStream_t stream) {
  const float* ex = (const float*)d_in[0];
  const float* ey = (const float*)d_in[1];
  char* ws = (char*)d_ws;
  __hip_bfloat16* An = (__hip_bfloat16*)ws;                              // 12.6 MB
  __hip_bfloat16* Bn = (__hip_bfloat16*)(ws + (size_t)NROWS * DIM * 2);  // 12.6 MB
  unsigned* rowKey = (unsigned*)(ws + (size_t)NROWS * DIM * 4);          // 32 KB
  unsigned* colKey = rowKey + NROWS;                                     // 32 KB

  normalize_kernel<<<4096, 256, 0, stream>>>(ex, ey, An, Bn, rowKey);
  dim3 grid(NROWS / BM, NROWS / BN);
  gemm_max_kernel<<<grid, 512, 0, stream>>>(An, Bn, rowKey, colKey);
  finalize_kernel<<<2, 256, 0, stream>>>(rowKey, colKey, (float*)d_out);
}